// Round 1
// baseline (794.944 us; speedup 1.0000x reference)
//
#include <hip/hip_runtime.h>
#include <hip/hip_bf16.h>

#define SENS 200
#define DM 128
#define SEQ 96
#define NB 8
#define BS (NB*SEQ)            // 768
#define NTOT (BS*SENS)         // 153600
#define TH 0.01f
#define BN_EPS 1e-5f

// ---------------- K1: mean over 64 attention maps ----------------
__global__ void attn_mean_kernel(const float* __restrict__ attn, float* __restrict__ mapA) {
    int idx = blockIdx.x * 256 + threadIdx.x;
    if (idx >= SENS * SENS) return;
    float s = 0.f;
    #pragma unroll 8
    for (int q = 0; q < 64; ++q) s += attn[(size_t)q * SENS * SENS + idx];
    mapA[idx] = s * (1.0f / 64.0f);
}

// ---------------- K2: symmetrize + clamp + degree ----------------
__global__ void build_map_kernel(const float* __restrict__ supports, const float* __restrict__ mapA,
                                 float* __restrict__ M, float* __restrict__ deg) {
    __shared__ float red[256];
    int m = blockIdx.x, map = blockIdx.y, j = threadIdx.x;
    const float* src = (map == 0) ? supports : mapA;
    float v = 0.f;
    if (j < SENS) {
        float sym = (m >= j) ? src[m * SENS + j] : src[j * SENS + m];
        float a = fabsf(sym);
        v = (a > TH) ? a : 0.f;
        M[(size_t)map * SENS * SENS + m * SENS + j] = v;
    }
    red[j] = v;
    __syncthreads();
    for (int off = 128; off > 0; off >>= 1) {
        if (j < off) red[j] += red[j + off];
        __syncthreads();
    }
    if (j == 0) deg[map * SENS + m] = red[0] + 1.0f;   // + self-loop
}

// ---------------- K3: An = D^-1/2 (M+I) D^-1/2 ----------------
__global__ void an_kernel(const float* __restrict__ M, const float* __restrict__ deg,
                          float* __restrict__ An) {
    int m = blockIdx.x, map = blockIdx.y, j = threadIdx.x;
    if (j >= SENS) return;
    float dm = deg[map * SENS + m], dj = deg[map * SENS + j];
    float rm = dm > 0.f ? rsqrtf(dm) : 0.f;
    float rj = dj > 0.f ? rsqrtf(dj) : 0.f;
    float a = M[(size_t)map * SENS * SENS + m * SENS + j] + ((m == j) ? 1.f : 0.f);
    An[(size_t)map * SENS * SENS + m * SENS + j] = rm * a * rj;
}

// ---------------- K4: layer-summed weights/bias ----------------
__global__ void wsum_kernel(const float* __restrict__ W_conv, const float* __restrict__ b_conv,
                            float* __restrict__ Wsum, float* __restrict__ bsum) {
    int idx = blockIdx.x * 256 + threadIdx.x;
    if (idx < 2 * DM * DM) {
        int map = idx / (DM * DM), r = idx % (DM * DM);
        Wsum[idx] = W_conv[(size_t)map * 2 * DM * DM + r]
                  + W_conv[(size_t)map * 2 * DM * DM + DM * DM + r];
    } else if (idx < 2 * DM * DM + 2 * DM) {
        int k = idx - 2 * DM * DM;
        int map = k / DM, g = k % DM;
        bsum[k] = b_conv[(map * 2) * DM + g] + b_conv[(map * 2 + 1) * DM + g];
    }
}

__global__ void zero_kernel(float* __restrict__ p) {
    p[blockIdx.x * 256 + threadIdx.x] = 0.f;
}

// ---------------- K5: h = An * xr * Wsum + bsum ----------------
// grid (14, 768): blockIdx.x -> (mt = bx%7, map = bx/7), blockIdx.y = bs.
// Per block: t_tile[32m x 128f] = An[m-tile,:] @ xr[bs]  (n-chunked via LDS),
// then h_tile = t_tile @ Wsum + bsum, written to global h.
__global__ __launch_bounds__(256) void hconv_kernel(
    const float* __restrict__ x, const float* __restrict__ An,
    const float* __restrict__ Wsum, const float* __restrict__ bsum,
    float* __restrict__ h)
{
    __shared__ float xs[32][128];     // xr chunk
    __shared__ float Atile[32][32];   // An tile [ml][nl]
    __shared__ float ts[32][128];     // t = An @ xr tile

    const int bx = blockIdx.x;
    const int mt = bx % 7, map = bx / 7;
    const int bs = blockIdx.y;
    const int b = bs / SEQ, s = bs % SEQ;
    const int m0 = mt * 32;
    const int mrows = (m0 + 32 <= SENS) ? 32 : (SENS - m0);
    const int t = threadIdx.x;
    const int tx = t & 31, ty = t >> 5;
    const int f4 = tx * 4, m4 = ty * 4;

    float acc[4][4];
    #pragma unroll
    for (int j = 0; j < 4; ++j)
        #pragma unroll
        for (int i = 0; i < 4; ++i) acc[j][i] = 0.f;

    const float* Ap = An + (size_t)map * SENS * SENS;

    for (int nc = 0; nc < SENS; nc += 32) {
        const int nrows = (nc + 32 <= SENS) ? 32 : (SENS - nc);
        // stage xr rows [nc, nc+32) : 1024 float4 loads
        for (int idx = t; idx < 32 * 32; idx += 256) {
            int nl = idx >> 5, fq = idx & 31;
            float4 v = make_float4(0.f, 0.f, 0.f, 0.f);
            if (nl < nrows)
                v = *(const float4*)&x[(((size_t)b * SENS + (nc + nl)) * SEQ + s) * DM + fq * 4];
            *(float4*)&xs[nl][fq * 4] = v;
        }
        // stage An tile
        for (int idx = t; idx < 32 * 32; idx += 256) {
            int ml = idx >> 5, nl = idx & 31;
            Atile[ml][nl] = (ml < mrows && nl < nrows) ? Ap[(m0 + ml) * SENS + nc + nl] : 0.f;
        }
        __syncthreads();
        #pragma unroll 4
        for (int nl = 0; nl < 32; ++nl) {
            float4 xv = *(const float4*)&xs[nl][f4];
            float av[4];
            #pragma unroll
            for (int j = 0; j < 4; ++j) av[j] = Atile[m4 + j][nl];
            #pragma unroll
            for (int j = 0; j < 4; ++j) {
                acc[j][0] += av[j] * xv.x;
                acc[j][1] += av[j] * xv.y;
                acc[j][2] += av[j] * xv.z;
                acc[j][3] += av[j] * xv.w;
            }
        }
        __syncthreads();
    }

    // t_tile -> LDS
    #pragma unroll
    for (int j = 0; j < 4; ++j)
        *(float4*)&ts[m4 + j][f4] = make_float4(acc[j][0], acc[j][1], acc[j][2], acc[j][3]);
    __syncthreads();

    // h_tile = t_tile @ Wsum + bsum   (g columns = f4..f4+3)
    const float* Wp = Wsum + map * DM * DM;
    const int g4 = f4;
    float4 bv = *(const float4*)&bsum[map * DM + g4];
    float hacc[4][4];
    #pragma unroll
    for (int j = 0; j < 4; ++j) { hacc[j][0] = bv.x; hacc[j][1] = bv.y; hacc[j][2] = bv.z; hacc[j][3] = bv.w; }
    for (int f = 0; f < DM; ++f) {
        float4 w = *(const float4*)&Wp[f * DM + g4];
        #pragma unroll
        for (int j = 0; j < 4; ++j) {
            float a = ts[m4 + j][f];
            hacc[j][0] += a * w.x; hacc[j][1] += a * w.y;
            hacc[j][2] += a * w.z; hacc[j][3] += a * w.w;
        }
    }
    float* hp = h + ((size_t)map * NTOT + (size_t)bs * SENS + m0) * DM;
    #pragma unroll
    for (int j = 0; j < 4; ++j) {
        if (m4 + j < mrows)
            *(float4*)&hp[(size_t)(m4 + j) * DM + g4] =
                make_float4(hacc[j][0], hacc[j][1], hacc[j][2], hacc[j][3]);
    }
}

// ---------------- K6: BN batch stats ----------------
__global__ __launch_bounds__(256) void bnstats_kernel(const float* __restrict__ h,
                                                      float* __restrict__ bn_sum,
                                                      float* __restrict__ bn_sumsq) {
    __shared__ float reds[128], redq[128];
    int map = blockIdx.y;
    int r0 = blockIdx.x * 256;
    int t = threadIdx.x, g = t & 127, rh = t >> 7;
    const float* hp = h + (size_t)map * NTOT * DM;
    float sa = 0.f, qa = 0.f;
    for (int j = 0; j < 128; ++j) {
        float v = hp[(size_t)(r0 + rh + 2 * j) * DM + g];
        sa += v; qa += v * v;
    }
    if (rh == 1) { reds[g] = sa; redq[g] = qa; }
    __syncthreads();
    if (rh == 0) {
        atomicAdd(&bn_sum[map * DM + g], sa + reds[g]);
        atomicAdd(&bn_sumsq[map * DM + g], qa + redq[g]);
    }
}

// ---------------- K7: BN finalize -> scale/shift ----------------
__global__ void bnfin_kernel(const float* __restrict__ bn_sum, const float* __restrict__ bn_sumsq,
                             const float* __restrict__ gamma, const float* __restrict__ beta,
                             float* __restrict__ scale, float* __restrict__ shift) {
    int t = threadIdx.x;   // t = map*128+g
    float mu = bn_sum[t] * (1.0f / (float)NTOT);
    float var = bn_sumsq[t] * (1.0f / (float)NTOT) - mu * mu;
    float inv = rsqrtf(var + BN_EPS);
    float sc = gamma[t] * inv;
    scale[t] = sc;
    shift[t] = beta[t] - mu * sc;
}

// ---------------- K8: relu(bn(h)) concat @ W_out + b_out, relu, transpose-out ----------------
__global__ __launch_bounds__(256) void out_kernel(
    const float* __restrict__ h, const float* __restrict__ scale, const float* __restrict__ shift,
    const float* __restrict__ W_out, const float* __restrict__ b_out, float* __restrict__ out)
{
    __shared__ float a[32][256];
    int r0 = blockIdx.x * 32, t = threadIdx.x;
    for (int map = 0; map < 2; ++map) {
        const float* hp = h + (size_t)map * NTOT * DM;
        for (int idx = t; idx < 32 * DM; idx += 256) {
            int ml = idx >> 7, g = idx & 127;
            float v = hp[(size_t)(r0 + ml) * DM + g];
            v = v * scale[map * DM + g] + shift[map * DM + g];
            a[ml][map * DM + g] = fmaxf(v, 0.f);
        }
    }
    __syncthreads();
    int tx = t & 31, ty = t >> 5;
    int d4 = tx * 4, m4 = ty * 4;
    float4 bv = *(const float4*)&b_out[d4];
    float acc2[4][4];
    #pragma unroll
    for (int j = 0; j < 4; ++j) { acc2[j][0] = bv.x; acc2[j][1] = bv.y; acc2[j][2] = bv.z; acc2[j][3] = bv.w; }
    for (int c = 0; c < 256; ++c) {
        float4 w = *(const float4*)&W_out[(size_t)c * DM + d4];
        #pragma unroll
        for (int j = 0; j < 4; ++j) {
            float av = a[m4 + j][c];
            acc2[j][0] += av * w.x; acc2[j][1] += av * w.y;
            acc2[j][2] += av * w.z; acc2[j][3] += av * w.w;
        }
    }
    #pragma unroll
    for (int j = 0; j < 4; ++j) {
        int r = r0 + m4 + j;
        int bsI = r / SENS, n = r % SENS;
        int b = bsI / SEQ, s = bsI % SEQ;
        float4 o = make_float4(fmaxf(acc2[j][0], 0.f), fmaxf(acc2[j][1], 0.f),
                               fmaxf(acc2[j][2], 0.f), fmaxf(acc2[j][3], 0.f));
        *(float4*)&out[(((size_t)b * SENS + n) * SEQ + s) * DM + d4] = o;
    }
}

extern "C" void kernel_launch(void* const* d_in, const int* in_sizes, int n_in,
                              void* d_out, int out_size, void* d_ws, size_t ws_size,
                              hipStream_t stream) {
    const float* x        = (const float*)d_in[0];
    const float* attn     = (const float*)d_in[1];
    const float* supports = (const float*)d_in[2];
    const float* W_conv   = (const float*)d_in[3];
    const float* b_conv   = (const float*)d_in[4];
    const float* gamma    = (const float*)d_in[5];
    const float* beta     = (const float*)d_in[6];
    const float* W_out    = (const float*)d_in[7];
    const float* b_out    = (const float*)d_in[8];
    float* out = (float*)d_out;
    float* ws  = (float*)d_ws;

    // workspace layout (floats)
    float* mapA  = ws;              // 40000
    float* M     = ws + 40000;      // 80000
    float* deg   = ws + 120000;     // 400 (padded to 448)
    float* An    = ws + 120448;     // 80000
    float* Wsum  = ws + 200448;     // 32768
    float* bsum  = ws + 233216;     // 256
    float* bnsum = ws + 233472;     // 256
    float* bnsq  = ws + 233728;     // 256 (contiguous with bnsum for zeroing)
    float* scale = ws + 233984;     // 256
    float* shift = ws + 234240;     // 256
    float* h     = ws + 234496;     // 2*153600*128 = 39321600  (total ~158.3 MB)

    attn_mean_kernel<<<(SENS * SENS + 255) / 256, 256, 0, stream>>>(attn, mapA);
    build_map_kernel<<<dim3(SENS, 2), 256, 0, stream>>>(supports, mapA, M, deg);
    an_kernel<<<dim3(SENS, 2), 256, 0, stream>>>(M, deg, An);
    wsum_kernel<<<(2 * DM * DM + 2 * DM + 255) / 256, 256, 0, stream>>>(W_conv, b_conv, Wsum, bsum);
    zero_kernel<<<2, 256, 0, stream>>>(bnsum);   // zeros bnsum(256)+bnsq(256)
    hconv_kernel<<<dim3(14, BS), 256, 0, stream>>>(x, An, Wsum, bsum, h);
    bnstats_kernel<<<dim3(NTOT / 256, 2), 256, 0, stream>>>(h, bnsum, bnsq);
    bnfin_kernel<<<1, 256, 0, stream>>>(bnsum, bnsq, gamma, beta, scale, shift);
    out_kernel<<<NTOT / 32, 256, 0, stream>>>(h, scale, shift, W_out, b_out, out);
}

// Round 2
// 375.370 us; speedup vs baseline: 2.1178x; 2.1178x over previous
//
#include <hip/hip_runtime.h>

#define SENS 200
#define DM 128
#define SEQ 96
#define NB 8
#define BS 768           // NB*SEQ
#define NTOT 153600      // BS*SENS
#define TH 0.01f
#define BN_EPS 1e-5f
#define NPAD 208         // padded sensor rows (13*16)
#define KPAD 224         // padded K dim for An columns (7*32)
#define XWROW 232        // LDS row stride (elements) for XWT[g][n]
#define HROW 136         // LDS row stride for h_lds[m][g]

typedef __attribute__((ext_vector_type(8))) __bf16 bf16x8;
typedef __attribute__((ext_vector_type(4))) float f32x4;

__device__ __forceinline__ f32x4 mfma16(bf16x8 a, bf16x8 b, f32x4 c) {
    return __builtin_amdgcn_mfma_f32_16x16x32_bf16(a, b, c, 0, 0, 0);
}

// ---------------- mean over 64 attention maps ----------------
__global__ void attn_mean_kernel(const float* __restrict__ attn, float* __restrict__ mapA) {
    int idx = blockIdx.x * 256 + threadIdx.x;
    if (idx >= SENS * SENS) return;
    float s = 0.f;
    #pragma unroll 8
    for (int q = 0; q < 64; ++q) s += attn[(size_t)q * SENS * SENS + idx];
    mapA[idx] = s * (1.0f / 64.0f);
}

// ---------------- symmetrize + clamp + degree ----------------
__global__ void build_map_kernel(const float* __restrict__ supports, const float* __restrict__ mapA,
                                 float* __restrict__ M, float* __restrict__ deg) {
    __shared__ float red[256];
    int m = blockIdx.x, map = blockIdx.y, j = threadIdx.x;
    const float* src = (map == 0) ? supports : mapA;
    float v = 0.f;
    if (j < SENS) {
        float sym = (m >= j) ? src[m * SENS + j] : src[j * SENS + m];
        float a = fabsf(sym);
        v = (a > TH) ? a : 0.f;
        M[(size_t)map * SENS * SENS + m * SENS + j] = v;
    }
    red[j] = v;
    __syncthreads();
    for (int off = 128; off > 0; off >>= 1) {
        if (j < off) red[j] += red[j + off];
        __syncthreads();
    }
    if (j == 0) deg[map * SENS + m] = red[0] + 1.0f;   // + self-loop
}

// ---------------- An (bf16, zero-padded to 208x224) ----------------
__global__ void anbf_kernel(const float* __restrict__ M, const float* __restrict__ deg,
                            __bf16* __restrict__ Anb) {
    const int m = blockIdx.x, map = blockIdx.y, j = threadIdx.x;
    if (j >= KPAD) return;
    float val = 0.f;
    if (m < SENS && j < SENS) {
        float dm = deg[map * SENS + m], dj = deg[map * SENS + j];
        float a = M[((size_t)map * SENS + m) * SENS + j] + ((m == j) ? 1.f : 0.f);
        val = rsqrtf(dm) * a * rsqrtf(dj);
    }
    Anb[((size_t)map * NPAD + m) * KPAD + j] = (__bf16)val;
}

// ---------------- weights: Wsum^T, W_out^T (bf16), bias sums, zero BN acc ----------------
__global__ void prepw_kernel(const float* __restrict__ W_conv, const float* __restrict__ b_conv,
                             const float* __restrict__ W_out,
                             __bf16* __restrict__ Wt, __bf16* __restrict__ Wot,
                             float* __restrict__ bsum, float* __restrict__ bnacc) {
    const int idx = blockIdx.x * 256 + threadIdx.x;
    if (idx < 32768) {                       // Wt[map][g][f] = sum_l W_conv[map][l][f][g]
        const int map = idx >> 14, rem = idx & 16383, g = rem >> 7, f = rem & 127;
        const float* wp = W_conv + (size_t)map * 2 * DM * DM + f * DM + g;
        Wt[idx] = (__bf16)(wp[0] + wp[DM * DM]);
    } else if (idx < 65536) {                // Wot[d][c] = W_out[c][d]
        const int k = idx - 32768, d = k >> 8, c = k & 255;
        Wot[k] = (__bf16)W_out[c * DM + d];
    } else if (idx < 65792) {                // bsum[map][g]
        const int k = idx - 65536, map = k >> 7, g = k & 127;
        bsum[k] = b_conv[(map * 2) * DM + g] + b_conv[(map * 2 + 1) * DM + g];
    } else if (idx < 66304) {                // zero bn accumulators (512 floats)
        bnacc[idx - 65792] = 0.f;
    }
}

// ---------------- x -> xt[bs][n][f] bf16 ----------------
__global__ void xt_kernel(const float* __restrict__ x, __bf16* __restrict__ xt) {
    const int n = blockIdx.x, b = blockIdx.y;
    const int t = threadIdx.x, f = t & 127, sl = t >> 7;
    const float* xp = x + ((size_t)b * SENS + n) * SEQ * DM;
    for (int s0 = 0; s0 < SEQ; s0 += 2) {
        const int s = s0 + sl;
        xt[(((size_t)b * SEQ + s) * SENS + n) * DM + f] = (__bf16)xp[(size_t)s * DM + f];
    }
}

// ---------------- fused conv: h = An @ (xr @ Wsum) + b, + BN partial stats ----------------
// grid (768, 2), block 512 (8 waves). LDS holds xw^T[g][n] between phases, then h tile.
__global__ __launch_bounds__(512) void conv_kernel(
    const __bf16* __restrict__ xt, const __bf16* __restrict__ Anb,
    const __bf16* __restrict__ Wt, const float* __restrict__ bsum,
    __bf16* __restrict__ h, float* __restrict__ bnacc)
{
    __shared__ __bf16 smem[128 * XWROW];     // 59392 B
    const int bs = blockIdx.x, map = blockIdx.y;
    const int t = threadIdx.x, w = t >> 6, lane = t & 63;
    const int l15 = lane & 15, quad = lane >> 4;
    const f32x4 fz = {0.f, 0.f, 0.f, 0.f};

    // ---- phase 1: XWT[g][n] = (xt[bs] @ Wsum[map])^T ----
    const __bf16* xb = xt + (size_t)bs * SENS * DM;
    const __bf16* Wb = Wt + (size_t)map * DM * DM;
    for (int sidx = w; sidx < 14; sidx += 8) {
        const int n0 = sidx * 16;
        if (n0 >= NPAD) {                    // strip 13: zero pad columns 208..223
            #pragma unroll
            for (int ct = 0; ct < 8; ++ct)
                #pragma unroll
                for (int r = 0; r < 4; ++r)
                    smem[(ct * 16 + l15) * XWROW + n0 + quad * 4 + r] = (__bf16)0.f;
            continue;
        }
        const int nrow = n0 + l15;
        bf16x8 afr[4];
        if (nrow < SENS) {
            #pragma unroll
            for (int kc = 0; kc < 4; ++kc)
                afr[kc] = *(const bf16x8*)(xb + (size_t)nrow * DM + kc * 32 + quad * 8);
        } else {
            #pragma unroll
            for (int kc = 0; kc < 4; ++kc)
                #pragma unroll
                for (int j = 0; j < 8; ++j) afr[kc][j] = (__bf16)0.f;
        }
        #pragma unroll
        for (int ct = 0; ct < 8; ++ct) {
            f32x4 acc = fz;
            const __bf16* wp = Wb + (size_t)(ct * 16 + l15) * DM + quad * 8;
            #pragma unroll
            for (int kc = 0; kc < 4; ++kc)
                acc = mfma16(afr[kc], *(const bf16x8*)(wp + kc * 32), acc);
            #pragma unroll
            for (int r = 0; r < 4; ++r)
                smem[(ct * 16 + l15) * XWROW + n0 + quad * 4 + r] = (__bf16)acc[r];
        }
    }
    __syncthreads();

    // ---- phase 2: h_tile = An[m-strips] @ XWT^T ----
    f32x4 acc2[2][8];
    #pragma unroll
    for (int r2 = 0; r2 < 2; ++r2) {
        #pragma unroll
        for (int ct = 0; ct < 8; ++ct) acc2[r2][ct] = fz;
        const int sidx = w + r2 * 8;
        if (sidx >= 13) continue;
        const int m0 = sidx * 16;
        const __bf16* Ap = Anb + ((size_t)map * NPAD + m0 + l15) * KPAD + quad * 8;
        #pragma unroll 2
        for (int kc = 0; kc < 7; ++kc) {
            bf16x8 a = *(const bf16x8*)(Ap + kc * 32);
            #pragma unroll
            for (int ct = 0; ct < 8; ++ct) {
                bf16x8 b = *(const bf16x8*)(smem + (size_t)(ct * 16 + l15) * XWROW + kc * 32 + quad * 8);
                acc2[r2][ct] = mfma16(a, b, acc2[r2][ct]);
            }
        }
    }
    __syncthreads();       // all XWT reads done; smem becomes h_lds[m][HROW]

    #pragma unroll
    for (int r2 = 0; r2 < 2; ++r2) {
        const int sidx = w + r2 * 8;
        if (sidx >= 13) continue;
        const int m0 = sidx * 16;
        #pragma unroll
        for (int ct = 0; ct < 8; ++ct) {
            const float bias = bsum[map * DM + ct * 16 + l15];
            #pragma unroll
            for (int r = 0; r < 4; ++r)
                smem[(size_t)(m0 + quad * 4 + r) * HROW + ct * 16 + l15] =
                    (__bf16)(acc2[r2][ct][r] + bias);
        }
    }
    __syncthreads();

    // coalesced global h write (rows m<200 only)
    __bf16* hp = h + ((size_t)map * BS + bs) * NPAD * DM;
    for (int idx = t; idx < SENS * (DM / 8); idx += 512) {
        const int m = idx >> 4, ch = idx & 15;
        *(bf16x8*)(hp + (size_t)m * DM + ch * 8) =
            *(const bf16x8*)(smem + (size_t)m * HROW + ch * 8);
    }
    // BN partial stats
    if (t < 256) {
        const int g = t & 127, sh = t >> 7;
        float s = 0.f;
        for (int m = 0; m < SENS; ++m) {
            float v = (float)smem[(size_t)m * HROW + g];
            s += sh ? v * v : v;
        }
        atomicAdd(&bnacc[sh * 256 + map * DM + g], s);
    }
}

// ---------------- BN finalize ----------------
__global__ void bnfin_kernel(const float* __restrict__ bnacc,
                             const float* __restrict__ gamma, const float* __restrict__ beta,
                             float* __restrict__ scale, float* __restrict__ shift) {
    int t = threadIdx.x;
    float mu = bnacc[t] * (1.f / (float)NTOT);
    float var = bnacc[256 + t] * (1.f / (float)NTOT) - mu * mu;
    float sc = gamma[t] * rsqrtf(var + BN_EPS);
    scale[t] = sc;
    shift[t] = beta[t] - mu * sc;
}

// ---------------- out = relu( relu(bn(h)) cat @ W_out + b_out ), transposed store ----------------
// grid 2400, block 256 (4 waves), 64-row x 128-d tile, K=256 in 8 chunks.
__global__ __launch_bounds__(256) void out_kernel(
    const __bf16* __restrict__ h, const __bf16* __restrict__ Wot,
    const float* __restrict__ scale, const float* __restrict__ shift,
    const float* __restrict__ b_out, float* __restrict__ out)
{
    __shared__ __bf16 As[64 * 56];
    __shared__ float sc_s[256], sh_s[256];
    const int t = threadIdx.x, w = t >> 6, lane = t & 63;
    const int l15 = lane & 15, quad = lane >> 4;
    const int r0 = blockIdx.x * 64;
    sc_s[t] = scale[t]; sh_s[t] = shift[t];

    f32x4 acc[8];
    #pragma unroll
    for (int ct = 0; ct < 8; ++ct) {
        float b0 = b_out[ct * 16 + l15];
        f32x4 av = {b0, b0, b0, b0};
        acc[ct] = av;
    }
    for (int kc = 0; kc < 8; ++kc) {
        const int map = kc >> 2, g0 = (kc & 3) * 32;
        __syncthreads();
        {   // stage 64 rows x 32 c of BN-applied relu(h) into As
            const int rl = t >> 2, gp = t & 3;
            const unsigned r = r0 + rl;
            const unsigned bsI = r / 200u, n = r % 200u;
            bf16x8 v = *(const bf16x8*)(h + (((size_t)map * BS + bsI) * NPAD + n) * DM + g0 + gp * 8);
            bf16x8 o;
            #pragma unroll
            for (int j = 0; j < 8; ++j) {
                const int c = map * DM + g0 + gp * 8 + j;
                float f = (float)v[j] * sc_s[c] + sh_s[c];
                o[j] = (__bf16)fmaxf(f, 0.f);
            }
            *(bf16x8*)(As + rl * 56 + gp * 8) = o;
        }
        __syncthreads();
        bf16x8 a = *(const bf16x8*)(As + (w * 16 + l15) * 56 + quad * 8);
        #pragma unroll
        for (int ct = 0; ct < 8; ++ct) {
            bf16x8 b = *(const bf16x8*)(Wot + (size_t)(ct * 16 + l15) * 256 + kc * 32 + quad * 8);
            acc[ct] = mfma16(a, b, acc[ct]);
        }
    }
    #pragma unroll
    for (int r = 0; r < 4; ++r) {
        const unsigned row = r0 + w * 16 + quad * 4 + r;
        const unsigned bsI = row / 200u, n = row % 200u;
        const unsigned b = bsI / 96u, s = bsI % 96u;
        float* op = out + (((size_t)b * SENS + n) * SEQ + s) * DM;
        #pragma unroll
        for (int ct = 0; ct < 8; ++ct)
            op[ct * 16 + l15] = fmaxf(acc[ct][r], 0.f);
    }
}

extern "C" void kernel_launch(void* const* d_in, const int* in_sizes, int n_in,
                              void* d_out, int out_size, void* d_ws, size_t ws_size,
                              hipStream_t stream) {
    const float* x        = (const float*)d_in[0];
    const float* attn     = (const float*)d_in[1];
    const float* supports = (const float*)d_in[2];
    const float* W_conv   = (const float*)d_in[3];
    const float* b_conv   = (const float*)d_in[4];
    const float* gamma    = (const float*)d_in[5];
    const float* beta     = (const float*)d_in[6];
    const float* W_out    = (const float*)d_in[7];
    const float* b_out    = (const float*)d_in[8];
    float* out = (float*)d_out;
    char* base = (char*)d_ws;

    float*  mapA  = (float*)(base + 0);          // 160000 B
    float*  Mbuf  = (float*)(base + 160000);     // 320000 B
    float*  deg   = (float*)(base + 480000);     // 2048 B
    float*  bnacc = (float*)(base + 482048);     // 2048 B (512 f: sums | sumsqs)
    float*  scale = (float*)(base + 484096);     // 1024 B
    float*  shiftv= (float*)(base + 485120);     // 1024 B
    float*  bsum  = (float*)(base + 486144);     // 1024 B
    __bf16* Wt    = (__bf16*)(base + 487168);    // 65536 B
    __bf16* Wot   = (__bf16*)(base + 552704);    // 65536 B
    __bf16* Anb   = (__bf16*)(base + 618240);    // 186368 B
    __bf16* xt    = (__bf16*)(base + 1048576);   // 39321600 B
    __bf16* h     = (__bf16*)(base + 40370176);  // 81788928 B  (end ~122.2 MB)

    attn_mean_kernel<<<157, 256, 0, stream>>>(attn, mapA);
    build_map_kernel<<<dim3(SENS, 2), 256, 0, stream>>>(supports, mapA, Mbuf, deg);
    anbf_kernel<<<dim3(NPAD, 2), 256, 0, stream>>>(Mbuf, deg, Anb);
    prepw_kernel<<<260, 256, 0, stream>>>(W_conv, b_conv, W_out, Wt, Wot, bsum, bnacc);
    xt_kernel<<<dim3(SENS, NB), 256, 0, stream>>>(x, xt);
    conv_kernel<<<dim3(BS, 2), 512, 0, stream>>>(xt, Anb, Wt, bsum, h, bnacc);
    bnfin_kernel<<<1, 256, 0, stream>>>(bnacc, gamma, beta, scale, shiftv);
    out_kernel<<<NTOT / 64, 256, 0, stream>>>(h, Wot, scale, shiftv, b_out, out);
}

// Round 3
// 312.134 us; speedup vs baseline: 2.5468x; 1.2026x over previous
//
#include <hip/hip_runtime.h>

#define SENS 200
#define DM 128
#define SEQ 96
#define NB 8
#define BS 768            // NB*SEQ
#define NTOT 153600       // BS*SENS
#define TH 0.01f
#define BN_EPS 1e-5f
#define MPAD 224          // padded sensor dim (7*32)
#define XWROW 236         // LDS row stride for xw[g][n] (472 B: 8-mod-16 -> b64 conflict-free)
#define ASROW 76          // LDS row stride for As[m][c] in out (152 B)

typedef __attribute__((ext_vector_type(8)))  __bf16 bf16x8;
typedef __attribute__((ext_vector_type(4)))  __bf16 bf16x4;
typedef __attribute__((ext_vector_type(16))) float  f32x16;

__device__ __forceinline__ f32x16 mfma32(bf16x8 a, bf16x8 b, f32x16 c) {
    return __builtin_amdgcn_mfma_f32_32x32x16_bf16(a, b, c, 0, 0, 0);
}
__device__ __forceinline__ bf16x8 join8(bf16x4 a, bf16x4 b) {
    bf16x8 r;
    #pragma unroll
    for (int j = 0; j < 4; ++j) { r[j] = a[j]; r[j + 4] = b[j]; }
    return r;
}

// ---------------- mean over 64 attention maps ----------------
__global__ void attn_mean_kernel(const float* __restrict__ attn, float* __restrict__ mapA) {
    int idx = blockIdx.x * 256 + threadIdx.x;
    if (idx >= SENS * SENS) return;
    float s = 0.f;
    #pragma unroll 8
    for (int q = 0; q < 64; ++q) s += attn[(size_t)q * SENS * SENS + idx];
    mapA[idx] = s * (1.0f / 64.0f);
}

// ---------------- symmetrize + clamp + degree ----------------
__global__ void build_map_kernel(const float* __restrict__ supports, const float* __restrict__ mapA,
                                 float* __restrict__ M, float* __restrict__ deg) {
    __shared__ float red[256];
    int m = blockIdx.x, map = blockIdx.y, j = threadIdx.x;
    const float* src = (map == 0) ? supports : mapA;
    float v = 0.f;
    if (j < SENS) {
        float sym = (m >= j) ? src[m * SENS + j] : src[j * SENS + m];
        float a = fabsf(sym);
        v = (a > TH) ? a : 0.f;
        M[(size_t)map * SENS * SENS + m * SENS + j] = v;
    }
    red[j] = v;
    __syncthreads();
    for (int off = 128; off > 0; off >>= 1) {
        if (j < off) red[j] += red[j + off];
        __syncthreads();
    }
    if (j == 0) deg[map * SENS + m] = red[0] + 1.0f;   // + self-loop
}

// ---------------- An bf16, K-sliced layout Anb[map][kc14][m 224][16] ----------------
__global__ void anbf_kernel(const float* __restrict__ M, const float* __restrict__ deg,
                            __bf16* __restrict__ Anb) {
    const int m = blockIdx.x, map = blockIdx.y, j = threadIdx.x;
    if (j >= MPAD) return;
    float val = 0.f;
    if (m < SENS && j < SENS) {
        float a = M[((size_t)map * SENS + m) * SENS + j] + ((m == j) ? 1.f : 0.f);
        val = rsqrtf(deg[map * SENS + m]) * a * rsqrtf(deg[map * SENS + j]);
    }
    Anb[(((size_t)map * 14 + (j >> 4)) * MPAD + m) * 16 + (j & 15)] = (__bf16)val;
}

// ---------------- weights (K-sliced), bias sums, BN-acc zero ----------------
// Wt[map][kc8][g128][16] = sum_l W_conv[map][l][f][g];  Wot[kc16][d128][16] = W_out[c][d]
__global__ void prepw_kernel(const float* __restrict__ W_conv, const float* __restrict__ b_conv,
                             const float* __restrict__ W_out,
                             __bf16* __restrict__ Wt, __bf16* __restrict__ Wot,
                             float* __restrict__ bsum, float* __restrict__ bnacc) {
    const int idx = blockIdx.x * 256 + threadIdx.x;
    if (idx < 32768) {
        const int map = idx >> 14, g = (idx >> 7) & 127, f = idx & 127;
        const float* wp = W_conv + (size_t)map * 2 * DM * DM + f * DM + g;
        Wt[(((size_t)map * 8 + (f >> 4)) * DM + g) * 16 + (f & 15)] = (__bf16)(wp[0] + wp[DM * DM]);
    } else if (idx < 65536) {
        const int k = idx - 32768, d = k >> 8, c = k & 255;
        Wot[(((size_t)(c >> 4)) * DM + d) * 16 + (c & 15)] = (__bf16)W_out[c * DM + d];
    } else if (idx < 65792) {
        const int k = idx - 65536, map = k >> 7, g = k & 127;
        bsum[k] = b_conv[(map * 2) * DM + g] + b_conv[(map * 2 + 1) * DM + g];
    } else if (idx < 66304) {
        bnacc[idx - 65792] = 0.f;
    }
}

// ---------------- x -> xk[bs][kc8][n 224][16] bf16 (rows >=200 zero) ----------------
__global__ void xk_kernel(const float* __restrict__ x, __bf16* __restrict__ xk) {
    const int bs = blockIdx.x;
    const int b = bs / SEQ, s = bs % SEQ;
    const int t = threadIdx.x, f = t & 127, nh = t >> 7;
    __bf16* xo = xk + ((size_t)bs * 8 + (f >> 4)) * MPAD * 16 + (f & 15);
    const float* xp = x + ((size_t)b * SENS) * SEQ * DM + (size_t)s * DM + f;
    for (int n0 = 0; n0 < MPAD; n0 += 2) {
        const int n = n0 + nh;
        float v = (n < SENS) ? xp[(size_t)n * SEQ * DM] : 0.f;
        xo[(size_t)n * 16] = (__bf16)v;
    }
}

// ---------------- fused conv: xw^T = Wt@xr^T (LDS), h = An@xw (tiled global), BN stats ----------------
// grid (768, 2), 448 threads = 7 waves. Phase1: wave w = n-tile w. Phase2: wave w = m-strip w.
__global__ __launch_bounds__(448) void conv_kernel(
    const __bf16* __restrict__ xk, const __bf16* __restrict__ Anb,
    const __bf16* __restrict__ Wt, const float* __restrict__ bsum,
    __bf16* __restrict__ h, float* __restrict__ bnacc)
{
    __shared__ __bf16 xw[128 * XWROW];            // 60416 B
    const int bs = blockIdx.x, map = blockIdx.y;
    const int t = threadIdx.x, w = t >> 6, lane = t & 63;
    const int l31 = lane & 31, hi = lane >> 5;

    // ---- phase 1: xw[g][n] = sum_f Wt[g][f] * xr[n][f], n-tile = w ----
    {
        f32x16 acc[4];
        #pragma unroll
        for (int gs = 0; gs < 4; ++gs)
            #pragma unroll
            for (int r = 0; r < 16; ++r) acc[gs][r] = 0.f;
        const __bf16* xb = xk + (((size_t)bs * 8) * MPAD + w * 32 + l31) * 16 + hi * 8;
        const __bf16* wb = Wt + (((size_t)map * 8) * DM + l31) * 16 + hi * 8;
        #pragma unroll
        for (int kc = 0; kc < 8; ++kc) {
            bf16x8 bfrag = *(const bf16x8*)(xb + (size_t)kc * MPAD * 16);
            #pragma unroll
            for (int gs = 0; gs < 4; ++gs) {
                bf16x8 afrag = *(const bf16x8*)(wb + ((size_t)kc * DM + gs * 32) * 16);
                acc[gs] = mfma32(afrag, bfrag, acc[gs]);
            }
        }
        #pragma unroll
        for (int gs = 0; gs < 4; ++gs)
            #pragma unroll
            for (int r = 0; r < 16; ++r) {
                const int row = gs * 32 + (r & 3) + 8 * (r >> 2) + 4 * hi;
                xw[row * XWROW + w * 32 + l31] = (__bf16)acc[gs][r];
            }
    }
    __syncthreads();

    // ---- phase 2: h-strip w = An[strip] @ xw^T, + bias, tiled store, BN partials ----
    f32x16 acc2[4];
    #pragma unroll
    for (int ct = 0; ct < 4; ++ct)
        #pragma unroll
        for (int r = 0; r < 16; ++r) acc2[ct][r] = 0.f;
    {
        const __bf16* ab = Anb + (((size_t)map * 14) * MPAD + w * 32 + l31) * 16 + hi * 8;
        for (int kc = 0; kc < 14; ++kc) {
            bf16x8 afrag = *(const bf16x8*)(ab + (size_t)kc * MPAD * 16);
            #pragma unroll
            for (int ct = 0; ct < 4; ++ct) {
                const __bf16* p = &xw[(ct * 32 + l31) * XWROW + kc * 16 + hi * 8];
                bf16x8 bfrag = join8(*(const bf16x4*)p, *(const bf16x4*)(p + 4));
                acc2[ct] = mfma32(afrag, bfrag, acc2[ct]);
            }
        }
    }
    float bsn[4], bsq[4];
    #pragma unroll
    for (int ct = 0; ct < 4; ++ct) {
        const float bias = bsum[map * DM + ct * 32 + l31];
        bf16x8 h0, h1;
        float s = 0.f, q = 0.f;
        #pragma unroll
        for (int r = 0; r < 16; ++r) {
            const float v = acc2[ct][r] + bias;
            if (r < 8) h0[r] = (__bf16)v; else h1[r - 8] = (__bf16)v;
            const int m = w * 32 + (r & 3) + 8 * (r >> 2) + 4 * hi;
            if (m < SENS) { s += v; q += v * v; }
        }
        __bf16* hp = h + ((((size_t)(bs * 2 + map) * 7 + w) * 4 + ct) * 64 + lane) * 16;
        *(bf16x8*)hp = h0;
        *(bf16x8*)(hp + 8) = h1;
        s += __shfl_xor(s, 32);
        q += __shfl_xor(q, 32);
        bsn[ct] = s; bsq[ct] = q;
    }
    __syncthreads();                     // xw reads done; reuse as reduction buffer
    float* red = (float*)xw;             // [2][128][7]
    if (hi == 0) {
        #pragma unroll
        for (int ct = 0; ct < 4; ++ct) {
            red[(ct * 32 + l31) * 7 + w] = bsn[ct];
            red[(128 + ct * 32 + l31) * 7 + w] = bsq[ct];
        }
    }
    __syncthreads();
    if (t < 256) {
        const int sq = t >> 7, g = t & 127;
        float s = 0.f;
        #pragma unroll
        for (int k = 0; k < 7; ++k) s += red[(sq * 128 + g) * 7 + k];
        atomicAdd(&bnacc[sq * 256 + map * DM + g], s);
    }
}

// ---------------- BN finalize ----------------
__global__ void bnfin_kernel(const float* __restrict__ bnacc,
                             const float* __restrict__ gamma, const float* __restrict__ beta,
                             float* __restrict__ scale, float* __restrict__ shift) {
    int t = threadIdx.x;
    float mu = bnacc[t] * (1.f / (float)NTOT);
    float var = bnacc[256 + t] * (1.f / (float)NTOT) - mu * mu;
    float sc = gamma[t] * rsqrtf(var + BN_EPS);
    scale[t] = sc;
    shift[t] = beta[t] - mu * sc;
}

// ---------------- out: relu( relu(bn(h)) cat @ W_out + b_out ), transposed store ----------------
// grid 768 (block = bs), 512 threads = 8 waves; wave w: d-tile = w&3, strips {w>>2, +2, +4, +6}
__global__ __launch_bounds__(512) void out_kernel(
    const __bf16* __restrict__ h, const __bf16* __restrict__ Wot,
    const float* __restrict__ scale, const float* __restrict__ shift,
    const float* __restrict__ b_out, float* __restrict__ out)
{
    __shared__ __bf16 As[MPAD * ASROW];           // 34048 B
    __shared__ float sc_s[256], sh_s[256];
    const int bs = blockIdx.x;
    const int b = bs / SEQ, s = bs % SEQ;
    const int t = threadIdx.x, w = t >> 6, lane = t & 63;
    const int l31 = lane & 31, hi = lane >> 5;
    const int dct = w & 3, sbase = w >> 2;
    if (t < 256) { sc_s[t] = scale[t]; sh_s[t] = shift[t]; }

    f32x16 acc[4];
    {
        const float bo = b_out[dct * 32 + l31];
        #pragma unroll
        for (int i = 0; i < 4; ++i)
            #pragma unroll
            for (int r = 0; r < 16; ++r) acc[i][r] = bo;
    }
    for (int chunk = 0; chunk < 4; ++chunk) {
        const int map = chunk >> 1;
        __syncthreads();
        {   // stage 224 rows x 64 c of relu(bn(h)) from tiled layout
            const __bf16* hb = h + ((size_t)(bs * 2 + map) * 28 + (chunk & 1) * 2) * 1024;
            #pragma unroll
            for (int it = 0; it < 4; ++it) {
                const int idx = it * 512 + t;
                if (idx < 1792) {
                    const int half = idx & 1, lane_s = (idx >> 1) & 63;
                    const int ctl = (idx >> 7) & 1, strip = idx >> 8;
                    bf16x8 v = *(const bf16x8*)(hb + ((size_t)strip * 4 + ctl) * 1024 + lane_s * 16 + half * 8);
                    const int cl = ctl * 32 + (lane_s & 31);
                    const int cg = map * DM + (chunk & 1) * 64 + cl;
                    const float scv = sc_s[cg], shv = sh_s[cg];
                    const int mbase = strip * 32 + 4 * (lane_s >> 5) + 16 * half;
                    #pragma unroll
                    for (int q2 = 0; q2 < 8; ++q2) {
                        const int row = mbase + (q2 & 3) + 8 * (q2 >> 2);
                        const float fv = (float)v[q2] * scv + shv;
                        As[row * ASROW + cl] = (__bf16)fmaxf(fv, 0.f);
                    }
                }
            }
        }
        __syncthreads();
        #pragma unroll
        for (int kc = 0; kc < 4; ++kc) {
            bf16x8 bfrag = *(const bf16x8*)(Wot + (((size_t)(chunk * 4 + kc)) * DM + dct * 32 + l31) * 16 + hi * 8);
            #pragma unroll
            for (int i = 0; i < 4; ++i) {
                const int strip = sbase + 2 * i;
                if (strip >= 7) break;
                const __bf16* ap = &As[(strip * 32 + l31) * ASROW + kc * 16 + hi * 8];
                bf16x8 afrag = join8(*(const bf16x4*)ap, *(const bf16x4*)(ap + 4));
                acc[i] = mfma32(afrag, bfrag, acc[i]);
            }
        }
    }
    #pragma unroll
    for (int i = 0; i < 4; ++i) {
        const int strip = sbase + 2 * i;
        if (strip >= 7) break;
        #pragma unroll
        for (int r = 0; r < 16; ++r) {
            const int m = strip * 32 + (r & 3) + 8 * (r >> 2) + 4 * hi;
            if (m < SENS)
                out[(((size_t)b * SENS + m) * SEQ + s) * DM + dct * 32 + l31] = fmaxf(acc[i][r], 0.f);
        }
    }
}

extern "C" void kernel_launch(void* const* d_in, const int* in_sizes, int n_in,
                              void* d_out, int out_size, void* d_ws, size_t ws_size,
                              hipStream_t stream) {
    const float* x        = (const float*)d_in[0];
    const float* attn     = (const float*)d_in[1];
    const float* supports = (const float*)d_in[2];
    const float* W_conv   = (const float*)d_in[3];
    const float* b_conv   = (const float*)d_in[4];
    const float* gamma    = (const float*)d_in[5];
    const float* beta     = (const float*)d_in[6];
    const float* W_out    = (const float*)d_in[7];
    const float* b_out    = (const float*)d_in[8];
    float* out = (float*)d_out;
    char* base = (char*)d_ws;

    float*  mapA  = (float*)(base + 0);          // 160000
    float*  Mbuf  = (float*)(base + 160000);     // 320000
    float*  deg   = (float*)(base + 480000);     // 1600
    float*  bnacc = (float*)(base + 481664);     // 2048
    float*  scale = (float*)(base + 483712);     // 1024
    float*  shiftv= (float*)(base + 484736);     // 1024
    float*  bsum  = (float*)(base + 485760);     // 1024
    __bf16* Wt    = (__bf16*)(base + 486784);    // 65536
    __bf16* Wot   = (__bf16*)(base + 552320);    // 65536
    __bf16* Anb   = (__bf16*)(base + 617856);    // 200704
    __bf16* xk    = (__bf16*)(base + 1048576);   // 44040192
    __bf16* h     = (__bf16*)(base + 45088768);  // 88080384 (end ~127 MiB)

    attn_mean_kernel<<<157, 256, 0, stream>>>(attn, mapA);
    build_map_kernel<<<dim3(SENS, 2), 256, 0, stream>>>(supports, mapA, Mbuf, deg);
    anbf_kernel<<<dim3(MPAD, 2), 256, 0, stream>>>(Mbuf, deg, Anb);
    prepw_kernel<<<260, 256, 0, stream>>>(W_conv, b_conv, W_out, Wt, Wot, bsum, bnacc);
    xk_kernel<<<BS, 256, 0, stream>>>(x, xk);
    conv_kernel<<<dim3(BS, 2), 448, 0, stream>>>(xk, Anb, Wt, bsum, h, bnacc);
    bnfin_kernel<<<1, 256, 0, stream>>>(bnacc, gamma, beta, scale, shiftv);
    out_kernel<<<BS, 512, 0, stream>>>(h, Wot, scale, shiftv, b_out, out);
}

// Round 4
// 282.939 us; speedup vs baseline: 2.8096x; 1.1032x over previous
//
#include <hip/hip_runtime.h>

#define SENS 200
#define DM 128
#define SEQ 96
#define NB 8
#define BS 768            // NB*SEQ
#define NTOT 153600       // BS*SENS
#define TH 0.01f
#define BN_EPS 1e-5f
#define MPAD 224          // padded sensor dim for M/rows (7*32)
#define KP 208            // effective K for phase2 (13*16): cols >=200 are zero
#define XWROW 212         // LDS row stride (424 B: gcd(106,32)=2 -> 2-way, free)
#define ASROW 76          // LDS row stride for As[m][c] in out (152 B)

typedef __attribute__((ext_vector_type(8)))  __bf16 bf16x8;
typedef __attribute__((ext_vector_type(4)))  __bf16 bf16x4;
typedef __attribute__((ext_vector_type(16))) float  f32x16;

__device__ __forceinline__ f32x16 mfma32(bf16x8 a, bf16x8 b, f32x16 c) {
    return __builtin_amdgcn_mfma_f32_32x32x16_bf16(a, b, c, 0, 0, 0);
}
__device__ __forceinline__ bf16x8 join8(bf16x4 a, bf16x4 b) {
    bf16x8 r;
    #pragma unroll
    for (int j = 0; j < 4; ++j) { r[j] = a[j]; r[j + 4] = b[j]; }
    return r;
}

// ---------------- mean over 64 attention maps ----------------
__global__ void attn_mean_kernel(const float* __restrict__ attn, float* __restrict__ mapA) {
    int idx = blockIdx.x * 256 + threadIdx.x;
    if (idx >= SENS * SENS) return;
    float s = 0.f;
    #pragma unroll 8
    for (int q = 0; q < 64; ++q) s += attn[(size_t)q * SENS * SENS + idx];
    mapA[idx] = s * (1.0f / 64.0f);
}

// ---------------- symmetrize + clamp + degree ----------------
__global__ void build_map_kernel(const float* __restrict__ supports, const float* __restrict__ mapA,
                                 float* __restrict__ M, float* __restrict__ deg) {
    __shared__ float red[256];
    int m = blockIdx.x, map = blockIdx.y, j = threadIdx.x;
    const float* src = (map == 0) ? supports : mapA;
    float v = 0.f;
    if (j < SENS) {
        float sym = (m >= j) ? src[m * SENS + j] : src[j * SENS + m];
        float a = fabsf(sym);
        v = (a > TH) ? a : 0.f;
        M[(size_t)map * SENS * SENS + m * SENS + j] = v;
    }
    red[j] = v;
    __syncthreads();
    for (int off = 128; off > 0; off >>= 1) {
        if (j < off) red[j] += red[j + off];
        __syncthreads();
    }
    if (j == 0) deg[map * SENS + m] = red[0] + 1.0f;   // + self-loop
}

// ---------------- fused prep: xk transform | An bf16 | weights/bias/bnacc ----------------
// grid 1476: [0,768) xk; [768,1216) anbf; [1216,1476) prepw.
__global__ __launch_bounds__(256) void prep2_kernel(
    const float* __restrict__ x, const float* __restrict__ M, const float* __restrict__ deg,
    const float* __restrict__ W_conv, const float* __restrict__ b_conv,
    const float* __restrict__ W_out,
    __bf16* __restrict__ xk, __bf16* __restrict__ Anb,
    __bf16* __restrict__ Wt, __bf16* __restrict__ Wot,
    float* __restrict__ bsum, float* __restrict__ bnacc)
{
    const int bid = blockIdx.x, t = threadIdx.x;
    if (bid < BS) {
        // x -> xk[bs][kc8][n 224][16] bf16 (rows >=200 zero)
        const int bs = bid, b = bs / SEQ, s = bs % SEQ;
        const int fq = t & 31, sub = t >> 5;
        const float* xp = x + ((size_t)b * SENS) * SEQ * DM + (size_t)s * DM + fq * 4;
        __bf16* xo = xk + ((size_t)bs * 8 + (fq >> 2)) * MPAD * 16 + (fq & 3) * 4;
        for (int n = sub; n < MPAD; n += 8) {
            float4 v = make_float4(0.f, 0.f, 0.f, 0.f);
            if (n < SENS) v = *(const float4*)(xp + (size_t)n * SEQ * DM);
            bf16x4 o;
            o[0] = (__bf16)v.x; o[1] = (__bf16)v.y; o[2] = (__bf16)v.z; o[3] = (__bf16)v.w;
            *(bf16x4*)(xo + (size_t)n * 16) = o;
        }
    } else if (bid < BS + 2 * MPAD) {
        // An bf16, K-sliced Anb[map][kc13][m 224][16]
        const int i = bid - BS, map = i / MPAD, m = i % MPAD;
        const int j = t;
        if (j < KP) {
            float val = 0.f;
            if (m < SENS && j < SENS) {
                float a = M[((size_t)map * SENS + m) * SENS + j] + ((m == j) ? 1.f : 0.f);
                val = rsqrtf(deg[map * SENS + m]) * a * rsqrtf(deg[map * SENS + j]);
            }
            Anb[(((size_t)map * 13 + (j >> 4)) * MPAD + m) * 16 + (j & 15)] = (__bf16)val;
        }
    } else {
        const int idx = (bid - (BS + 2 * MPAD)) * 256 + t;
        if (idx < 32768) {                       // Wt[map][kc8][g128][16] = sum_l W[map][l][f][g]
            const int map = idx >> 14, g = (idx >> 7) & 127, f = idx & 127;
            const float* wp = W_conv + (size_t)map * 2 * DM * DM + f * DM + g;
            Wt[(((size_t)map * 8 + (f >> 4)) * DM + g) * 16 + (f & 15)] = (__bf16)(wp[0] + wp[DM * DM]);
        } else if (idx < 65536) {                // Wot[kc16][d128][16] = W_out[c][d]
            const int k = idx - 32768, d = k >> 8, c = k & 255;
            Wot[(((size_t)(c >> 4)) * DM + d) * 16 + (c & 15)] = (__bf16)W_out[c * DM + d];
        } else if (idx < 65792) {
            const int k = idx - 65536, map = k >> 7, g = k & 127;
            bsum[k] = b_conv[(map * 2) * DM + g] + b_conv[(map * 2 + 1) * DM + g];
        } else if (idx < 66304) {
            bnacc[idx - 65792] = 0.f;
        }
    }
}

// ---------------- fused conv: xw = Wt@xr^T (LDS), h = An@xw, BN stats ----------------
// grid (768, 2), 448 threads = 7 waves. Two-pass tiling keeps 32 acc regs live.
__global__ __launch_bounds__(448) void conv_kernel(
    const __bf16* __restrict__ xk, const __bf16* __restrict__ Anb,
    const __bf16* __restrict__ Wt, const float* __restrict__ bsum,
    __bf16* __restrict__ h, float* __restrict__ bnacc)
{
    __shared__ __bf16 xw[128 * XWROW];            // 54272 B -> 3 blocks/CU
    const int bs = blockIdx.x, map = blockIdx.y;
    const int t = threadIdx.x, w = t >> 6, lane = t & 63;
    const int l31 = lane & 31, hi = lane >> 5;

    // ---- phase 1: xw[g][n] (n-tile = w), 2 passes of 2 g-tiles ----
    const __bf16* xb = xk + (((size_t)bs * 8) * MPAD + w * 32 + l31) * 16 + hi * 8;
    #pragma unroll
    for (int gh = 0; gh < 2; ++gh) {
        f32x16 acc[2];
        #pragma unroll
        for (int p = 0; p < 2; ++p)
            #pragma unroll
            for (int r = 0; r < 16; ++r) acc[p][r] = 0.f;
        const __bf16* wb = Wt + (((size_t)map * 8) * DM + gh * 64 + l31) * 16 + hi * 8;
        #pragma unroll
        for (int kc = 0; kc < 8; ++kc) {
            bf16x8 bfrag = *(const bf16x8*)(xb + (size_t)kc * MPAD * 16);
            #pragma unroll
            for (int p = 0; p < 2; ++p)
                acc[p] = mfma32(*(const bf16x8*)(wb + ((size_t)kc * DM + p * 32) * 16), bfrag, acc[p]);
        }
        if (w < 6 || l31 < 16) {                 // cols >= 208 never read
            #pragma unroll
            for (int p = 0; p < 2; ++p)
                #pragma unroll
                for (int r = 0; r < 16; ++r) {
                    const int row = gh * 64 + p * 32 + (r & 3) + 8 * (r >> 2) + 4 * hi;
                    xw[row * XWROW + w * 32 + l31] = (__bf16)acc[p][r];
                }
        }
    }
    __syncthreads();

    // ---- phase 2: h-strip w = An[strip] @ xw^T (K=208), 2 passes of 2 g-tiles ----
    float bsn[4], bsq[4];
    const __bf16* ab = Anb + (((size_t)map * 13) * MPAD + w * 32 + l31) * 16 + hi * 8;
    #pragma unroll
    for (int cth = 0; cth < 2; ++cth) {
        f32x16 acc2[2];
        #pragma unroll
        for (int p = 0; p < 2; ++p)
            #pragma unroll
            for (int r = 0; r < 16; ++r) acc2[p][r] = 0.f;
        #pragma unroll
        for (int kc = 0; kc < 13; ++kc) {
            bf16x8 afrag = *(const bf16x8*)(ab + (size_t)kc * MPAD * 16);
            #pragma unroll
            for (int p = 0; p < 2; ++p) {
                const __bf16* pp = &xw[((cth * 2 + p) * 32 + l31) * XWROW + kc * 16 + hi * 8];
                acc2[p] = mfma32(afrag, join8(*(const bf16x4*)pp, *(const bf16x4*)(pp + 4)), acc2[p]);
            }
        }
        #pragma unroll
        for (int p = 0; p < 2; ++p) {
            const int ct = cth * 2 + p;
            const float bias = bsum[map * DM + ct * 32 + l31];
            bf16x8 h0, h1;
            float s = 0.f, q = 0.f;
            #pragma unroll
            for (int r = 0; r < 16; ++r) {
                const float v = acc2[p][r] + bias;
                if (r < 8) h0[r] = (__bf16)v; else h1[r - 8] = (__bf16)v;
                const int m = w * 32 + (r & 3) + 8 * (r >> 2) + 4 * hi;
                if (m < SENS) { s += v; q += v * v; }
            }
            __bf16* hp = h + ((((size_t)(bs * 2 + map) * 7 + w) * 4 + ct) * 64 + lane) * 16;
            *(bf16x8*)hp = h0;
            *(bf16x8*)(hp + 8) = h1;
            s += __shfl_xor(s, 32);
            q += __shfl_xor(q, 32);
            bsn[ct] = s; bsq[ct] = q;
        }
    }
    __syncthreads();                     // xw reads done; reuse as reduction buffer
    float* red = (float*)xw;             // [2][128][7]
    if (hi == 0) {
        #pragma unroll
        for (int ct = 0; ct < 4; ++ct) {
            red[(ct * 32 + l31) * 7 + w] = bsn[ct];
            red[(128 + ct * 32 + l31) * 7 + w] = bsq[ct];
        }
    }
    __syncthreads();
    if (t < 256) {
        const int sq = t >> 7, g = t & 127;
        float s = 0.f;
        #pragma unroll
        for (int k = 0; k < 7; ++k) s += red[(sq * 128 + g) * 7 + k];
        atomicAdd(&bnacc[sq * 256 + map * DM + g], s);
    }
}

// ---------------- out: relu( relu(bn(h)) cat @ W_out + b_out ), BN-finalize fused ----------------
// grid 768 (block = bs), 512 threads = 8 waves; wave w: d-tile = w&3, strips {w>>2, +2, +4, +6}
__global__ __launch_bounds__(512) void out_kernel(
    const __bf16* __restrict__ h, const __bf16* __restrict__ Wot,
    const float* __restrict__ bnacc,
    const float* __restrict__ gamma, const float* __restrict__ beta,
    const float* __restrict__ b_out, float* __restrict__ out)
{
    __shared__ __bf16 As[MPAD * ASROW];           // 34048 B
    __shared__ float sc_s[256], sh_s[256];
    const int bs = blockIdx.x;
    const int b = bs / SEQ, s = bs % SEQ;
    const int t = threadIdx.x, w = t >> 6, lane = t & 63;
    const int l31 = lane & 31, hi = lane >> 5;
    const int dct = w & 3, sbase = w >> 2;
    if (t < 256) {                                // BN finalize, per-block (cheap, removes a launch)
        const float mu = bnacc[t] * (1.f / (float)NTOT);
        const float var = bnacc[256 + t] * (1.f / (float)NTOT) - mu * mu;
        const float sc = gamma[t] * rsqrtf(var + BN_EPS);
        sc_s[t] = sc;
        sh_s[t] = beta[t] - mu * sc;
    }

    f32x16 acc[4];
    {
        const float bo = b_out[dct * 32 + l31];
        #pragma unroll
        for (int i = 0; i < 4; ++i)
            #pragma unroll
            for (int r = 0; r < 16; ++r) acc[i][r] = bo;
    }
    for (int chunk = 0; chunk < 4; ++chunk) {
        const int map = chunk >> 1;
        __syncthreads();
        {   // stage 224 rows x 64 c of relu(bn(h)) from fragment-tiled h
            const __bf16* hb = h + ((size_t)(bs * 2 + map) * 28 + (chunk & 1) * 2) * 1024;
            #pragma unroll
            for (int it = 0; it < 4; ++it) {
                const int idx = it * 512 + t;
                if (idx < 1792) {
                    const int half = idx & 1, lane_s = (idx >> 1) & 63;
                    const int ctl = (idx >> 7) & 1, strip = idx >> 8;
                    bf16x8 v = *(const bf16x8*)(hb + ((size_t)strip * 4 + ctl) * 1024 + lane_s * 16 + half * 8);
                    const int cl = ctl * 32 + (lane_s & 31);
                    const int cg = map * DM + (chunk & 1) * 64 + cl;
                    const float scv = sc_s[cg], shv = sh_s[cg];
                    const int mbase = strip * 32 + 4 * (lane_s >> 5) + 16 * half;
                    #pragma unroll
                    for (int q2 = 0; q2 < 8; ++q2) {
                        const int row = mbase + (q2 & 3) + 8 * (q2 >> 2);
                        const float fv = (float)v[q2] * scv + shv;
                        As[row * ASROW + cl] = (__bf16)fmaxf(fv, 0.f);
                    }
                }
            }
        }
        __syncthreads();
        #pragma unroll
        for (int kc = 0; kc < 4; ++kc) {
            bf16x8 bfrag = *(const bf16x8*)(Wot + (((size_t)(chunk * 4 + kc)) * DM + dct * 32 + l31) * 16 + hi * 8);
            #pragma unroll
            for (int i = 0; i < 4; ++i) {
                const int strip = sbase + 2 * i;
                if (strip >= 7) break;
                const __bf16* ap = &As[(strip * 32 + l31) * ASROW + kc * 16 + hi * 8];
                acc[i] = mfma32(join8(*(const bf16x4*)ap, *(const bf16x4*)(ap + 4)), bfrag, acc[i]);
            }
        }
    }
    #pragma unroll
    for (int i = 0; i < 4; ++i) {
        const int strip = sbase + 2 * i;
        if (strip >= 7) break;
        #pragma unroll
        for (int r = 0; r < 16; ++r) {
            const int m = strip * 32 + (r & 3) + 8 * (r >> 2) + 4 * hi;
            if (m < SENS)
                out[(((size_t)b * SENS + m) * SEQ + s) * DM + dct * 32 + l31] = fmaxf(acc[i][r], 0.f);
        }
    }
}

extern "C" void kernel_launch(void* const* d_in, const int* in_sizes, int n_in,
                              void* d_out, int out_size, void* d_ws, size_t ws_size,
                              hipStream_t stream) {
    const float* x        = (const float*)d_in[0];
    const float* attn     = (const float*)d_in[1];
    const float* supports = (const float*)d_in[2];
    const float* W_conv   = (const float*)d_in[3];
    const float* b_conv   = (const float*)d_in[4];
    const float* gamma    = (const float*)d_in[5];
    const float* beta     = (const float*)d_in[6];
    const float* W_out    = (const float*)d_in[7];
    const float* b_out    = (const float*)d_in[8];
    float* out = (float*)d_out;
    char* base = (char*)d_ws;

    float*  mapA  = (float*)(base + 0);          // 160000
    float*  Mbuf  = (float*)(base + 160000);     // 320000
    float*  deg   = (float*)(base + 480000);     // 1600 (pad to 481664)
    float*  bnacc = (float*)(base + 481664);     // 2048
    float*  bsum  = (float*)(base + 483712);     // 1024
    __bf16* Wt    = (__bf16*)(base + 484736);    // 65536
    __bf16* Wot   = (__bf16*)(base + 550272);    // 65536
    __bf16* Anb   = (__bf16*)(base + 615808);    // 186368
    __bf16* xk    = (__bf16*)(base + 1048576);   // 44040192
    __bf16* h     = (__bf16*)(base + 45088768);  // 88080384 (end ~127 MiB)

    attn_mean_kernel<<<157, 256, 0, stream>>>(attn, mapA);
    build_map_kernel<<<dim3(SENS, 2), 256, 0, stream>>>(supports, mapA, Mbuf, deg);
    prep2_kernel<<<BS + 2 * MPAD + 260, 256, 0, stream>>>(x, Mbuf, deg, W_conv, b_conv, W_out,
                                                          xk, Anb, Wt, Wot, bsum, bnacc);
    conv_kernel<<<dim3(BS, 2), 448, 0, stream>>>(xk, Anb, Wt, bsum, h, bnacc);
    out_kernel<<<BS, 512, 0, stream>>>(h, Wot, bnacc, gamma, beta, b_out, out);
}